// Round 9
// baseline (77.268 us; speedup 1.0000x reference)
//
#include <hip/hip_runtime.h>

// RoI max-pool, channel-last, LPT-ordered dynamic work queue.
// features [4,256,38,38] f32, rois [512,5] f32, out [512,256,7,7] f32.
//
// ws: featT [4][1444][256] f32 | perm[512] int | qhead int
//
// Kernel 1: transpose features -> featT; block (0,0) also counting-sorts
//           ROI indices by DESCENDING hh into perm (LPT order) and zeroes
//           qhead.
// Kernel 2: 1024 persistent blocks pop units g from qhead. Unit =
//           (roi-rank g>>3, cg = g&3, ph = (g>>2)&1). 4 waves take p-rows
//           of the half; compile-time row width via switch(ww); stage in
//           LDS; coalesced flat writes.

#define NROIS 512
#define CCH   256
#define FH    38
#define FW    38
#define HW    (FH * FW)          // 1444
#define SCALE 0.0625f
#define NEGF  (-3.402823466e+38f)
#define NUNITS (NROIS * 8)       // 4096

#define FEATT_BYTES ((size_t)4 * HW * CCH * sizeof(float))   // 5,914,624

// ---------------- Kernel 1: transpose + LPT sort ----------------
__device__ __forceinline__ int roi_hh(const float* __restrict__ rr)
{
    int y1 = (int)(rr[2] * SCALE);
    int y2 = (int)(rr[4] * SCALE);
    y1 = min(max(y1, 0), FH - 1);
    y2 = min(max(y2, 0), FH - 1);
    return y2 - y1 + 1;          // 1..38
}

__global__ __launch_bounds__(256) void transpose_sort_kernel(
    const float* __restrict__ src, const float* __restrict__ rois,
    float* __restrict__ dst, int* __restrict__ perm, int* __restrict__ qhead)
{
    __shared__ float tile[4][257];
    __shared__ int hist[40];

    const int b  = blockIdx.y;
    const int s0 = blockIdx.x * 4;
    const int t  = threadIdx.x;                 // = channel

    const float4 v = *(const float4*)(src + ((size_t)(b * CCH + t)) * HW + s0);
    tile[0][t] = v.x; tile[1][t] = v.y; tile[2][t] = v.z; tile[3][t] = v.w;
    __syncthreads();

    const int s = t >> 6;                       // 0..3
    const int m = t & 63;
    float* drow = dst + ((size_t)b * HW + s0 + s) * CCH;
    #pragma unroll
    for (int k = 0; k < 4; ++k)
        drow[m + 64 * k] = tile[s][m + 64 * k];

    // ---- LPT sort of ROI indices by descending hh (one block only) ----
    if (blockIdx.x == 0 && blockIdx.y == 0) {
        if (t < 40) hist[t] = 0;
        __syncthreads();
        const int h0 = roi_hh(rois + t * 5);
        const int h1 = roi_hh(rois + (t + 256) * 5);
        atomicAdd(&hist[h0], 1);
        atomicAdd(&hist[h1], 1);
        __syncthreads();
        if (t == 0) {
            int acc = 0;
            for (int h = 38; h >= 1; --h) {     // descending hh
                const int c = hist[h];
                hist[h] = acc;
                acc += c;
            }
            *qhead = 0;
        }
        __syncthreads();
        perm[atomicAdd(&hist[h0], 1)] = t;
        perm[atomicAdd(&hist[h1], 1)] = t + 256;
    }
}

// ---------------- Kernel 2: pooling ----------------
template <int WW>
__device__ __forceinline__ void pool_one(
    const float* __restrict__ rb, int h, float (&acc)[7])
{
    for (int y = 0; y < h; ++y) {
        float v[WW];
        #pragma unroll
        for (int j = 0; j < WW; ++j) v[j] = rb[j * CCH];
        #pragma unroll
        for (int q = 0; q < 7; ++q) {
            const int xs = (q * WW) / 7;
            const int xe = ((q + 1) * WW + 6) / 7;
            #pragma unroll
            for (int j = xs; j < xe; ++j)
                acc[q] = fmaxf(acc[q], v[j]);
        }
        rb += (size_t)FW * CCH;
    }
}

template <int NB>
__device__ __forceinline__ void write_out(
    float* __restrict__ outb, const float (*__restrict__ sm)[65], int tid)
{
    #pragma unroll
    for (int flat = 0; flat < 64 * NB; flat += 256) {
        const int f = flat + tid;
        if (f < 64 * NB) {
            const int c = f / NB;               // compile-time magic div
            const int l = f - c * NB;
            outb[c * 49 + l] = sm[l][c];
        }
    }
}

__global__ __launch_bounds__(256) void roipool_kernel(
    const float* __restrict__ featT,
    const float* __restrict__ rois,
    const int* __restrict__ perm,
    int* __restrict__ qhead,
    float* __restrict__ out)
{
    __shared__ float smem[28][65];
    __shared__ int sQ;

    const int tid  = threadIdx.x;
    const int wv   = __builtin_amdgcn_readfirstlane(tid >> 6);
    const int lane = tid & 63;

    for (;;) {
        if (tid == 0) sQ = atomicAdd(qhead, 1);
        __syncthreads();
        const int g = sQ;
        if (g >= NUNITS) break;

        const int r  = perm[g >> 3];           // ROI index (LPT order)
        const int cg = g & 3;
        const int ph = (g >> 2) & 1;

        // ROI decode (uniform per block)
        const float* rr = rois + r * 5;
        const int bb = (int)rr[0];
        int x1 = (int)(rr[1] * SCALE);
        int y1 = (int)(rr[2] * SCALE);
        int x2 = (int)(rr[3] * SCALE);
        int y2 = (int)(rr[4] * SCALE);
        x1 = min(max(x1, 0), FW - 1);
        y1 = min(max(y1, 0), FH - 1);
        x2 = min(max(x2, 0), FW - 1);
        y2 = min(max(y2, 0), FH - 1);
        const int hh = y2 - y1 + 1;
        const int ww = x2 - x1 + 1;            // 1..38, block-uniform

        const int p = 4 * ph + wv;             // one p-row per wave
        if (p < 7) {
            const int ys = y1 + (p * hh) / 7;
            const int h  = (y1 + ((p + 1) * hh + 6) / 7) - ys;

            const float* rb0 = featT + (size_t)bb * HW * CCH + cg * 64 + lane
                             + (size_t)(ys * FW + x1) * CCH;

            float acc[7];
            #pragma unroll
            for (int q = 0; q < 7; ++q) acc[q] = NEGF;

            switch (ww) {
                case  1: pool_one< 1>(rb0, h, acc); break;
                case  2: pool_one< 2>(rb0, h, acc); break;
                case  3: pool_one< 3>(rb0, h, acc); break;
                case  4: pool_one< 4>(rb0, h, acc); break;
                case  5: pool_one< 5>(rb0, h, acc); break;
                case  6: pool_one< 6>(rb0, h, acc); break;
                case  7: pool_one< 7>(rb0, h, acc); break;
                case  8: pool_one< 8>(rb0, h, acc); break;
                case  9: pool_one< 9>(rb0, h, acc); break;
                case 10: pool_one<10>(rb0, h, acc); break;
                case 11: pool_one<11>(rb0, h, acc); break;
                case 12: pool_one<12>(rb0, h, acc); break;
                case 13: pool_one<13>(rb0, h, acc); break;
                case 14: pool_one<14>(rb0, h, acc); break;
                case 15: pool_one<15>(rb0, h, acc); break;
                case 16: pool_one<16>(rb0, h, acc); break;
                case 17: pool_one<17>(rb0, h, acc); break;
                case 18: pool_one<18>(rb0, h, acc); break;
                case 19: pool_one<19>(rb0, h, acc); break;
                case 20: pool_one<20>(rb0, h, acc); break;
                case 21: pool_one<21>(rb0, h, acc); break;
                case 22: pool_one<22>(rb0, h, acc); break;
                case 23: pool_one<23>(rb0, h, acc); break;
                case 24: pool_one<24>(rb0, h, acc); break;
                case 25: pool_one<25>(rb0, h, acc); break;
                case 26: pool_one<26>(rb0, h, acc); break;
                case 27: pool_one<27>(rb0, h, acc); break;
                case 28: pool_one<28>(rb0, h, acc); break;
                case 29: pool_one<29>(rb0, h, acc); break;
                case 30: pool_one<30>(rb0, h, acc); break;
                case 31: pool_one<31>(rb0, h, acc); break;
                case 32: pool_one<32>(rb0, h, acc); break;
                case 33: pool_one<33>(rb0, h, acc); break;
                case 34: pool_one<34>(rb0, h, acc); break;
                case 35: pool_one<35>(rb0, h, acc); break;
                case 36: pool_one<36>(rb0, h, acc); break;
                case 37: pool_one<37>(rb0, h, acc); break;
                default: pool_one<38>(rb0, h, acc); break;
            }

            #pragma unroll
            for (int q = 0; q < 7; ++q)
                smem[wv * 7 + q][lane] = acc[q];
        }
        __syncthreads();

        float* outb = out + (size_t)r * (CCH * 49) + cg * (64 * 49) + ph * 28;
        if (ph == 0) write_out<28>(outb, smem, tid);
        else         write_out<21>(outb, smem, tid);
        __syncthreads();   // smem + sQ reuse next iteration
    }
}

// ---------------- Fallback (ws too small) ----------------
__global__ __launch_bounds__(256) void roipool_fallback(
    const float* __restrict__ feat,
    const float* __restrict__ rois,
    float* __restrict__ out)
{
    int idx = blockIdx.x * blockDim.x + threadIdx.x;
    int q = idx % 7;
    int t = idx / 7;
    int p = t % 7;
    t /= 7;
    int c = t % CCH;
    int n = t / CCH;

    const float* r = rois + n * 5;
    int b  = (int)r[0];
    int x1 = (int)(r[1] * SCALE);
    int y1 = (int)(r[2] * SCALE);
    int x2 = (int)(r[3] * SCALE);
    int y2 = (int)(r[4] * SCALE);
    x1 = min(max(x1, 0), FW - 1);
    y1 = min(max(y1, 0), FH - 1);
    x2 = min(max(x2, 0), FW - 1);
    y2 = min(max(y2, 0), FH - 1);
    int hh = y2 - y1 + 1, ww = x2 - x1 + 1;

    int ys = y1 + (p * hh) / 7, ye = y1 + ((p + 1) * hh + 6) / 7;
    int xs = x1 + (q * ww) / 7, xe = x1 + ((q + 1) * ww + 6) / 7;

    const float* base = feat + ((size_t)b * CCH + c) * HW;
    float m = NEGF;
    for (int y = ys; y < ye; ++y)
        for (int x = xs; x < xe; ++x)
            m = fmaxf(m, base[y * FW + x]);
    out[idx] = m;
}

extern "C" void kernel_launch(void* const* d_in, const int* in_sizes, int n_in,
                              void* d_out, int out_size, void* d_ws, size_t ws_size,
                              hipStream_t stream) {
    const float* feat = (const float*)d_in[0];
    const float* rois = (const float*)d_in[1];
    float* out = (float*)d_out;

    const size_t need = FEATT_BYTES + (NROIS + 1) * sizeof(int);
    if (ws_size < need) {
        const int total = NROIS * CCH * 49;
        roipool_fallback<<<(total + 255) / 256, 256, 0, stream>>>(feat, rois, out);
        return;
    }

    float* featT = (float*)d_ws;
    int*   perm  = (int*)((char*)d_ws + FEATT_BYTES);
    int*   qhead = perm + NROIS;

    dim3 tg(HW / 4, 4);                      // (361, 4)
    transpose_sort_kernel<<<tg, 256, 0, stream>>>(feat, rois, featT, perm, qhead);

    roipool_kernel<<<1024, 256, 0, stream>>>(featT, rois, perm, qhead, out);
}

// Round 10
// 26.994 us; speedup vs baseline: 2.8624x; 2.8624x over previous
//
#include <hip/hip_runtime.h>

// RoI max-pool, channel-last, cost-balanced static pairing.
// features [4,256,38,38] f32, rois [512,5] f32, out [512,256,7,7] f32.
//
// ws: featT [4][1444][256] f32 | perm[512] int
//
// Kernel 1: transpose features -> featT; block (0,0) also counting-sorts
//           ROI ids by DESCENDING cells=hh*ww (256-bucket quantized key).
// Kernel 2: 1024 blocks; block i processes items i and 2047-i, where
//           item = (rank = item>>2 into perm, cg = item&3). Snake pairing
//           makes every block's cost ~equal -> balanced per-CU sums.
//           Inner body identical to the verified R5 kernel.

#define NROIS 512
#define CCH   256
#define FH    38
#define FW    38
#define HW    (FH * FW)          // 1444
#define SCALE 0.0625f
#define NEGF  (-3.402823466e+38f)

#define FEATT_BYTES ((size_t)4 * HW * CCH * sizeof(float))   // 5,914,624

__device__ __forceinline__ void roi_decode(
    const float* __restrict__ rr,
    int& bb, int& x1, int& y1, int& x2, int& y2, int& hh, int& ww)
{
    bb = (int)rr[0];
    x1 = (int)(rr[1] * SCALE);
    y1 = (int)(rr[2] * SCALE);
    x2 = (int)(rr[3] * SCALE);
    y2 = (int)(rr[4] * SCALE);
    x1 = min(max(x1, 0), FW - 1);
    y1 = min(max(y1, 0), FH - 1);
    x2 = min(max(x2, 0), FW - 1);
    y2 = min(max(y2, 0), FH - 1);
    hh = y2 - y1 + 1;
    ww = x2 - x1 + 1;
}

// ---------------- Kernel 1: transpose + descending-cost sort ----------------
__global__ __launch_bounds__(256) void transpose_sort_kernel(
    const float* __restrict__ src, const float* __restrict__ rois,
    float* __restrict__ dst, int* __restrict__ perm)
{
    __shared__ float tile[4][257];

    const int b  = blockIdx.y;
    const int s0 = blockIdx.x * 4;
    const int t  = threadIdx.x;                 // = channel

    const float4 v = *(const float4*)(src + ((size_t)(b * CCH + t)) * HW + s0);
    tile[0][t] = v.x; tile[1][t] = v.y; tile[2][t] = v.z; tile[3][t] = v.w;
    __syncthreads();

    const int s = t >> 6;                       // 0..3
    const int m = t & 63;
    float* drow = dst + ((size_t)b * HW + s0 + s) * CCH;
    #pragma unroll
    for (int k = 0; k < 4; ++k)
        drow[m + 64 * k] = tile[s][m + 64 * k];

    // ---- counting sort by descending cells (one block only) ----
    if (blockIdx.x == 0 && blockIdx.y == 0) {
        __shared__ int hist[256];
        __shared__ int sc[256];

        hist[t] = 0;
        __syncthreads();

        int bb, x1, y1, x2, y2, hh, ww;
        roi_decode(rois + t * 5, bb, x1, y1, x2, y2, hh, ww);
        const int k0 = ((1444 - hh * ww) * 255) / 1443;       // 0 = biggest
        roi_decode(rois + (t + 256) * 5, bb, x1, y1, x2, y2, hh, ww);
        const int k1 = ((1444 - hh * ww) * 255) / 1443;

        atomicAdd(&hist[k0], 1);
        atomicAdd(&hist[k1], 1);
        __syncthreads();

        const int own = hist[t];
        sc[t] = own;
        __syncthreads();
        #pragma unroll
        for (int off = 1; off < 256; off <<= 1) {
            const int u = (t >= off) ? sc[t - off] : 0;
            __syncthreads();
            sc[t] += u;
            __syncthreads();
        }
        hist[t] = sc[t] - own;                  // exclusive prefix
        __syncthreads();

        perm[atomicAdd(&hist[k0], 1)] = t;
        perm[atomicAdd(&hist[k1], 1)] = t + 256;
    }
}

// ---------------- Kernel 2: pooling (R5 body, paired items) ----------------
template <int WW>
__device__ __forceinline__ void pool_one(
    const float* __restrict__ rb, int h, float (&acc)[7])
{
    for (int y = 0; y < h; ++y) {
        float v[WW];
        #pragma unroll
        for (int j = 0; j < WW; ++j) v[j] = rb[j * CCH];
        #pragma unroll
        for (int q = 0; q < 7; ++q) {
            const int xs = (q * WW) / 7;
            const int xe = ((q + 1) * WW + 6) / 7;
            #pragma unroll
            for (int j = xs; j < xe; ++j)
                acc[q] = fmaxf(acc[q], v[j]);
        }
        rb += (size_t)FW * CCH;
    }
}

__global__ __launch_bounds__(256) void roipool_kernel(
    const float* __restrict__ featT,
    const float* __restrict__ rois,
    const int* __restrict__ perm,
    float* __restrict__ out)
{
    __shared__ float smem[49][65];

    const int bid  = blockIdx.x;
    const int tid  = threadIdx.x;
    const int wv   = __builtin_amdgcn_readfirstlane(tid >> 6);
    const int lane = tid & 63;

    #pragma unroll 1
    for (int sit = 0; sit < 2; ++sit) {
        const int item = sit ? (2047 - bid) : bid;
        const int r  = perm[item >> 2];        // ROI id (sorted rank)
        const int cg = item & 3;

        int bb, x1, y1, x2, y2, hh, ww;
        roi_decode(rois + r * 5, bb, x1, y1, x2, y2, hh, ww);

        const float* fb = featT + (size_t)bb * HW * CCH + cg * 64 + lane
                        + (size_t)x1 * CCH;

        // wave wv handles p-rows {wv, wv+4}
        for (int p = wv; p < 7; p += 4) {
            const int ys = y1 + (p * hh) / 7;
            const int h  = (y1 + ((p + 1) * hh + 6) / 7) - ys;

            const float* rb0 = fb + (size_t)(ys * FW) * CCH;

            float acc[7];
            #pragma unroll
            for (int q = 0; q < 7; ++q) acc[q] = NEGF;

            switch (ww) {
                case  1: pool_one< 1>(rb0, h, acc); break;
                case  2: pool_one< 2>(rb0, h, acc); break;
                case  3: pool_one< 3>(rb0, h, acc); break;
                case  4: pool_one< 4>(rb0, h, acc); break;
                case  5: pool_one< 5>(rb0, h, acc); break;
                case  6: pool_one< 6>(rb0, h, acc); break;
                case  7: pool_one< 7>(rb0, h, acc); break;
                case  8: pool_one< 8>(rb0, h, acc); break;
                case  9: pool_one< 9>(rb0, h, acc); break;
                case 10: pool_one<10>(rb0, h, acc); break;
                case 11: pool_one<11>(rb0, h, acc); break;
                case 12: pool_one<12>(rb0, h, acc); break;
                case 13: pool_one<13>(rb0, h, acc); break;
                case 14: pool_one<14>(rb0, h, acc); break;
                case 15: pool_one<15>(rb0, h, acc); break;
                case 16: pool_one<16>(rb0, h, acc); break;
                case 17: pool_one<17>(rb0, h, acc); break;
                case 18: pool_one<18>(rb0, h, acc); break;
                case 19: pool_one<19>(rb0, h, acc); break;
                case 20: pool_one<20>(rb0, h, acc); break;
                case 21: pool_one<21>(rb0, h, acc); break;
                case 22: pool_one<22>(rb0, h, acc); break;
                case 23: pool_one<23>(rb0, h, acc); break;
                case 24: pool_one<24>(rb0, h, acc); break;
                case 25: pool_one<25>(rb0, h, acc); break;
                case 26: pool_one<26>(rb0, h, acc); break;
                case 27: pool_one<27>(rb0, h, acc); break;
                case 28: pool_one<28>(rb0, h, acc); break;
                case 29: pool_one<29>(rb0, h, acc); break;
                case 30: pool_one<30>(rb0, h, acc); break;
                case 31: pool_one<31>(rb0, h, acc); break;
                case 32: pool_one<32>(rb0, h, acc); break;
                case 33: pool_one<33>(rb0, h, acc); break;
                case 34: pool_one<34>(rb0, h, acc); break;
                case 35: pool_one<35>(rb0, h, acc); break;
                case 36: pool_one<36>(rb0, h, acc); break;
                case 37: pool_one<37>(rb0, h, acc); break;
                default: pool_one<38>(rb0, h, acc); break;
            }

            #pragma unroll
            for (int q = 0; q < 7; ++q)
                smem[p * 7 + q][lane] = acc[q];
        }
        __syncthreads();

        // coalesced flat writes: 64 ch * 49 bins
        float* outb = out + (size_t)r * (CCH * 49) + cg * (64 * 49);
        int flat = tid;
        int c  = tid / 49;
        int pq = tid - c * 49;
        #pragma unroll
        for (int k = 0; k < 13; ++k) {
            if (flat < 3136)
                outb[c * 49 + pq] = smem[pq][c];
            flat += 256;
            c += 5; pq += 11;           // 256 = 5*49 + 11
            if (pq >= 49) { pq -= 49; c += 1; }
        }
        __syncthreads();                // smem reused by next item
    }
}

// ---------------- Fallback (ws too small) ----------------
__global__ __launch_bounds__(256) void roipool_fallback(
    const float* __restrict__ feat,
    const float* __restrict__ rois,
    float* __restrict__ out)
{
    int idx = blockIdx.x * blockDim.x + threadIdx.x;
    int q = idx % 7;
    int t = idx / 7;
    int p = t % 7;
    t /= 7;
    int c = t % CCH;
    int n = t / CCH;

    int bb, x1, y1, x2, y2, hh, ww;
    roi_decode(rois + n * 5, bb, x1, y1, x2, y2, hh, ww);

    int ys = y1 + (p * hh) / 7, ye = y1 + ((p + 1) * hh + 6) / 7;
    int xs = x1 + (q * ww) / 7, xe = x1 + ((q + 1) * ww + 6) / 7;

    const float* base = feat + ((size_t)bb * CCH + c) * HW;
    float m = NEGF;
    for (int y = ys; y < ye; ++y)
        for (int x = xs; x < xe; ++x)
            m = fmaxf(m, base[y * FW + x]);
    out[idx] = m;
}

extern "C" void kernel_launch(void* const* d_in, const int* in_sizes, int n_in,
                              void* d_out, int out_size, void* d_ws, size_t ws_size,
                              hipStream_t stream) {
    const float* feat = (const float*)d_in[0];
    const float* rois = (const float*)d_in[1];
    float* out = (float*)d_out;

    const size_t need = FEATT_BYTES + NROIS * sizeof(int);
    if (ws_size < need) {
        const int total = NROIS * CCH * 49;
        roipool_fallback<<<(total + 255) / 256, 256, 0, stream>>>(feat, rois, out);
        return;
    }

    float* featT = (float*)d_ws;
    int*   perm  = (int*)((char*)d_ws + FEATT_BYTES);

    dim3 tg(HW / 4, 4);                      // (361, 4)
    transpose_sort_kernel<<<tg, 256, 0, stream>>>(feat, rois, featT, perm);

    roipool_kernel<<<1024, 256, 0, stream>>>(featT, rois, perm, out);
}